// Round 14
// baseline (159.722 us; speedup 1.0000x reference)
//
#include <hip/hip_runtime.h>
#include <hip/hip_bf16.h>
#include <stdint.h>

#define DEV __device__ __forceinline__

typedef float f32x4 __attribute__((ext_vector_type(4)));
typedef __bf16 bf16x8 __attribute__((ext_vector_type(8)));

DEV __bf16 tobf(float x){
  union { __hip_bfloat16 s; __bf16 b; } u; u.s = __float2bfloat16(x); return u.b;
}
DEV float bflo(uint32_t u){ return __uint_as_float(u << 16); }
DEV float bfhi(uint32_t u){ return __uint_as_float(u & 0xffff0000u); }
DEV float dot4(const float4& a, const float4& b){
  return a.x*b.x + a.y*b.y + a.z*b.z + a.w*b.w;
}
DEV bf16x8 pack8(const float4& a, const float4& b){
  bf16x8 r;
  r[0]=tobf(a.x); r[1]=tobf(a.y); r[2]=tobf(a.z); r[3]=tobf(a.w);
  r[4]=tobf(b.x); r[5]=tobf(b.y); r[6]=tobf(b.z); r[7]=tobf(b.w);
  return r;
}
DEV uint32_t f2bf2(float x, float y){
  union { __hip_bfloat16 b[2]; uint32_t u; } cv;
  cv.b[0] = __float2bfloat16(x); cv.b[1] = __float2bfloat16(y);
  return cv.u;
}
DEV float4 avg4(const float4& a, const float4& b){
  float4 r; r.x=0.5f*(a.x+b.x); r.y=0.5f*(a.y+b.y); r.z=0.5f*(a.z+b.z); r.w=0.5f*(a.w+b.w);
  return r;
}

// relative-coordinate values (matches reference _rel_index, f32 semantics)
DEV float relc(int j){
  if (j < 17) return (float)(j - 8);
  if (j < 22) return (float)(j - 19) * 3.4f;   // (i-2) * 17/5
  return 0.0f;
}
DEV int band_of(int t){ return t < 17 ? 0 : (t < 22 ? 1 : 2); }

// avgpool1d index map over the concatenated 23-axis -> 13 pooled slots.
template<int MODE> DEV void pool_map(int u, int& a, int& b){
  if (MODE == 0){ a = u; b = u; return; }
  if (u == 0){ a = 0; b = 0; }
  else if (u < 9){ a = 2*u - 1; b = 2*u; }
  else if (u == 9){ a = 17; b = 17; }
  else if (u < 12){ a = 2*u - 2; b = 2*u - 1; }
  else { a = 22; b = 22; }
}

DEV float interp_tab(const float* tab, int H, int h, int t, int u){
  float idx = relc(t) - relc(u) + 16.0f;
  float fl = floorf(idx);
  float ce = ceilf(idx);
  int fi = (int)fminf(fmaxf(fl, 0.f), 1088.f);
  int ci = (int)fminf(fmaxf(ce, 0.f), 1088.f);
  float w = idx - fl;
  return (1.0f - w) * tab[fi*H + h] + w * tab[ci*H + h];
}

// ---------------- QK^T quarter-partial (r11-proven flat-load body) ----------------
template<int MODE>
DEV void qk_group(int gm, int qt,
    const float* __restrict__ x0, const float* __restrict__ x1, const float* __restrict__ x2,
    float* __restrict__ SpB,
    float* Spart /*[4][32][33]*/, float* qnp /*[4][32]*/, float* knp /*[4][32]*/)
{
  constexpr int U = (MODE == 0) ? 23 : 13;
  constexpr int H = (MODE == 0) ? 1 : 3;
  int b, h, d;
  if (MODE == 0){ b = gm >> 6; h = 0; d = gm & 63; }
  else { b = gm / 192; int r = gm % 192; h = r >> 6; d = r & 63; }

  const int tid  = threadIdx.x;
  const int lane = tid & 63;
  const int w    = tid >> 6;
  const int lrow = lane & 15;
  const int kq   = lane >> 4;

  auto base_of = [&](int sel, int band) -> const float* {
    if (band == 0) return x0 + (size_t)((((sel*4 + b)*H + h)*64 + d)*17) * 1024;
    if (band == 1) return x1 + (size_t)((((sel*4 + b)*H + h)*64 + d)*5) * 1024;
    return x2 + (size_t)(((sel*4 + b)*H + h)*64 + d) * 1024;
  };
  const float* qb0 = base_of(0,0); const float* qb1 = base_of(0,1); const float* qb2 = base_of(0,2);
  const float* kb0 = base_of(1,0); const float* kb1 = base_of(1,1); const float* kb2 = base_of(1,2);

  auto rowp = [&](const float* r0, const float* r1, const float* r2, int t) -> const float* {
    if (t < 17) return r0 + (size_t)t * 1024;
    if (t < 22) return r1 + (size_t)(t - 17) * 1024;
    return r2;
  };

  const float* qr[2]; bool qv[2];
  #pragma unroll
  for (int mi = 0; mi < 2; ++mi){
    int t = mi*16 + lrow;
    qv[mi] = (t < 23);
    qr[mi] = qv[mi] ? rowp(qb0,qb1,qb2,t) : qb0;
  }
  const float* krA[2]; const float* krB[2]; bool kv[2];
  #pragma unroll
  for (int ni = 0; ni < 2; ++ni){
    int u = ni*16 + lrow;
    kv[ni] = (u < U);
    int au, bu; pool_map<MODE>(kv[ni] ? u : 0, au, bu);
    krA[ni] = rowp(kb0,kb1,kb2,au);
    krB[ni] = rowp(kb0,kb1,kb2,bu);
  }

  const int sbase = qt*256 + w*64 + kq*8;

  float4 qld[2][4];
  float4 kld[2][4];
  #pragma unroll
  for (int mi = 0; mi < 2; ++mi){
    #pragma unroll
    for (int kk = 0; kk < 2; ++kk){
      #pragma unroll
      for (int hf = 0; hf < 2; ++hf){
        qld[mi][kk*2+hf] = qv[mi] ? *(const float4*)(qr[mi] + sbase + kk*32 + hf*4)
                                  : float4{0,0,0,0};
      }
    }
  }
  if (MODE == 0){
    #pragma unroll
    for (int ni = 0; ni < 2; ++ni){
      #pragma unroll
      for (int kk = 0; kk < 2; ++kk){
        #pragma unroll
        for (int hf = 0; hf < 2; ++hf){
          kld[ni][kk*2+hf] = kv[ni] ? *(const float4*)(krA[ni] + sbase + kk*32 + hf*4)
                                    : float4{0,0,0,0};
        }
      }
    }
  } else {
    #pragma unroll
    for (int kk = 0; kk < 2; ++kk){
      #pragma unroll
      for (int hf = 0; hf < 2; ++hf){
        kld[0][kk*2+hf] = kv[0] ? *(const float4*)(krA[0] + sbase + kk*32 + hf*4)
                                : float4{0,0,0,0};
        kld[1][kk*2+hf] = kv[0] ? *(const float4*)(krB[0] + sbase + kk*32 + hf*4)
                                : float4{0,0,0,0};
      }
    }
  }

  f32x4 acc[2][2] = {};
  float qss[2] = {0.f, 0.f}, kss[2] = {0.f, 0.f};
  #pragma unroll
  for (int kk = 0; kk < 2; ++kk){
    bf16x8 qf[2], kf[2];
    #pragma unroll
    for (int mi = 0; mi < 2; ++mi){
      float4 v0 = qld[mi][kk*2], v1 = qld[mi][kk*2+1];
      qss[mi] += dot4(v0,v0) + dot4(v1,v1);
      qf[mi] = pack8(v0, v1);
    }
    if (MODE == 0){
      #pragma unroll
      for (int ni = 0; ni < 2; ++ni){
        float4 v0 = kld[ni][kk*2], v1 = kld[ni][kk*2+1];
        kss[ni] += dot4(v0,v0) + dot4(v1,v1);
        kf[ni] = pack8(v0, v1);
      }
    } else {
      float4 v0 = avg4(kld[0][kk*2], kld[1][kk*2]);
      float4 v1 = avg4(kld[0][kk*2+1], kld[1][kk*2+1]);
      kss[0] += dot4(v0,v0) + dot4(v1,v1);
      kf[0] = pack8(v0, v1);
    }
    #pragma unroll
    for (int mi = 0; mi < 2; ++mi){
      #pragma unroll
      for (int ni = 0; ni < 2; ++ni){
        if (MODE == 0 || ni == 0)
          acc[mi][ni] = __builtin_amdgcn_mfma_f32_16x16x32_bf16(qf[mi], kf[ni], acc[mi][ni], 0, 0, 0);
      }
    }
  }

  #pragma unroll
  for (int i = 0; i < 2; ++i){
    qss[i] += __shfl_xor(qss[i], 16); qss[i] += __shfl_xor(qss[i], 32);
    kss[i] += __shfl_xor(kss[i], 16); kss[i] += __shfl_xor(kss[i], 32);
  }
  if (lane < 16){
    qnp[w*32 + lane]      = qss[0];
    qnp[w*32 + 16 + lane] = qss[1];
    knp[w*32 + lane]      = kss[0];
    knp[w*32 + 16 + lane] = kss[1];
  }
  #pragma unroll
  for (int mi = 0; mi < 2; ++mi)
    #pragma unroll
    for (int ni = 0; ni < 2; ++ni)
      #pragma unroll
      for (int j = 0; j < 4; ++j)
        Spart[w*1056 + (mi*16 + kq*4 + j)*33 + ni*16 + lrow] = acc[mi][ni][j];
  __syncthreads();

  if (tid < 32){
    SpB[1024 + tid] = qnp[tid] + qnp[32+tid] + qnp[64+tid] + qnp[96+tid];
  } else if (tid < 64){
    int c = tid - 32;
    SpB[1056 + c] = knp[c] + knp[32+c] + knp[64+c] + knp[96+c];
  }
  {
    int r  = tid >> 3;
    int c0 = (tid & 7) * 4;
    float4 o;
    o.x = Spart[r*33+c0+0] + Spart[1056+r*33+c0+0] + Spart[2112+r*33+c0+0] + Spart[3168+r*33+c0+0];
    o.y = Spart[r*33+c0+1] + Spart[1056+r*33+c0+1] + Spart[2112+r*33+c0+1] + Spart[3168+r*33+c0+1];
    o.z = Spart[r*33+c0+2] + Spart[1056+r*33+c0+2] + Spart[2112+r*33+c0+2] + Spart[3168+r*33+c0+2];
    o.w = Spart[r*33+c0+3] + Spart[1056+r*33+c0+3] + Spart[2112+r*33+c0+3] + Spart[3168+r*33+c0+3];
    *(float4*)(SpB + r*32 + c0) = o;
  }
}

// ---------------- fused_a: qk4 [0,4096) + vconv [4096,6080) + prep [6080,7106) ----------------
__global__ __launch_bounds__(256, 4) void fused_a(
    const float* __restrict__ xh0, const float* __restrict__ xh1, const float* __restrict__ xh2,
    const float* __restrict__ xl0, const float* __restrict__ xl1, const float* __restrict__ xl2,
    const float* __restrict__ htab, const float* __restrict__ habs,
    const float* __restrict__ ltab, const float* __restrict__ labs,
    const float* __restrict__ hw, const float* __restrict__ lw,
    float* __restrict__ Sp, __hip_bfloat16* __restrict__ Vb,
    float* __restrict__ pe_h, float* __restrict__ pe_l,
    __hip_bfloat16* __restrict__ whb, __hip_bfloat16* __restrict__ wlb)
{
  __shared__ __align__(16) float Spart[4*32*33];
  __shared__ float qnp[4*32], knp[4*32];
  const int bid = blockIdx.x;
  const int tid = threadIdx.x;

  if (bid < 4096){
    int g = bid >> 2, qt = bid & 3;
    float* SpB = Sp + (size_t)bid * 1088;
    if (g < 256) qk_group<0>(g,       qt, xh0, xh1, xh2, SpB, Spart, qnp, knp);
    else         qk_group<1>(g - 256, qt, xl0, xl1, xl2, SpB, Spart, qnp, knp);
    return;
  }

  if (bid < 6080){
    const int vb_ = bid - 4096;
    auto vsrc = [&](int r, const float*& pa, const float*& pb){
      if (r < 5888){
        int gg = r / 23, u = r - gg*23;
        int b = gg >> 6, d = gg & 63;
        const float* v0 = xh0 + (size_t)(((8 + b)*64 + d)*17) * 1024;
        const float* v1 = xh1 + (size_t)(((8 + b)*64 + d)*5) * 1024;
        const float* v2 = xh2 + (size_t)((8 + b)*64 + d) * 1024;
        pa = (u < 17) ? v0 + (size_t)u*1024 : (u < 22 ? v1 + (size_t)(u-17)*1024 : v2);
        pb = pa;
      } else {
        int rr = r - 5888;
        int gm = rr / 13, u = rr - gm*13;
        int b = gm / 192, rem = gm % 192, h = rem >> 6, d = rem & 63;
        const float* v0 = xl0 + (size_t)((((8 + b)*3 + h)*64 + d)*17) * 1024;
        const float* v1 = xl1 + (size_t)((((8 + b)*3 + h)*64 + d)*5) * 1024;
        const float* v2 = xl2 + (size_t)(((8 + b)*3 + h)*64 + d) * 1024;
        int au, bu; pool_map<1>(u, au, bu);
        pa = (au < 17) ? v0 + (size_t)au*1024 : (au < 22 ? v1 + (size_t)(au-17)*1024 : v2);
        pb = (bu < 17) ? v0 + (size_t)bu*1024 : (bu < 22 ? v1 + (size_t)(bu-17)*1024 : v2);
      }
    };
    const int c0 = tid * 4;
    float4 va[8], vbv[8]; bool two[8];
    #pragma unroll
    for (int i = 0; i < 8; ++i){
      int r = vb_*8 + i;
      const float *pa, *pb; vsrc(r, pa, pb);
      va[i] = *(const float4*)(pa + c0);
      two[i] = (pb != pa);
      vbv[i] = two[i] ? *(const float4*)(pb + c0) : va[i];
    }
    #pragma unroll
    for (int i = 0; i < 8; ++i){
      float4 a = two[i] ? avg4(va[i], vbv[i]) : va[i];
      uint2 o; o.x = f2bf2(a.x, a.y); o.y = f2bf2(a.z, a.w);
      *(uint2*)(Vb + (size_t)(vb_*8 + i)*1024 + c0) = o;
    }
    return;
  }

  const int pb_ = bid - 6080;
  if (pb_ < 1024){
    int i = (pb_*256 + tid)*8;
    const float* src; __hip_bfloat16* dst;
    if (i < 1048576){ src = hw + i; dst = whb + i; }
    else { src = lw + (i - 1048576); dst = wlb + (i - 1048576); }
    float4 x0 = *(const float4*)(src);
    float4 x1 = *(const float4*)(src + 4);
    uint4 o;
    o.x = f2bf2(x0.x, x0.y); o.y = f2bf2(x0.z, x0.w);
    o.z = f2bf2(x1.x, x1.y); o.w = f2bf2(x1.z, x1.w);
    *(uint4*)dst = o;
  } else if (pb_ == 1024){
    for (int j = tid; j < 529; j += 256){
      int t = j / 23, u = j % 23;
      pe_h[j] = interp_tab(htab, 1, 0, t, u) + habs[band_of(t)];
    }
  } else {
    for (int j = tid; j < 897; j += 256){
      int h = j / 299, r = j % 299, t = r / 13, u = r % 13;
      int a, b; pool_map<1>(u, a, b);
      pe_l[j] = 0.5f * (interp_tab(ltab, 3, h, t, a) + interp_tab(ltab, 3, h, t, b))
              + labs[band_of(t)*3 + h];
    }
  }
}

// ---------------- 256x256 8-phase counted-vmcnt GEMM (m201 template shape) ----------------
// M=15872 (62 tiles: 0..22 hifi, 23..61 lofi), N=1024 (4 tiles), K=1024 (16 x BK=64).
// 512 threads = 8 waves (2M x 4N); per-wave C = 128x64 as 2x2 quadrant-chunks of 64x32.
// LDS: [par][half] 128x64 bf16 for A and B = 128 KB. Per phase: vmcnt -> 12 ds_read ->
// stage 1 half-tile (2 gload_lds/thread) -> s_barrier -> setprio+16 MFMA -> s_barrier.
template<int N> DEV void vwait(){ asm volatile("s_waitcnt vmcnt(%0)" :: "n"(N) : "memory"); }

__global__ __launch_bounds__(512, 2) void gemm8(
    const __hip_bfloat16* __restrict__ A,
    const __hip_bfloat16* __restrict__ Wh, const __hip_bfloat16* __restrict__ Wl,
    __hip_bfloat16* __restrict__ VW)
{
  __shared__ __hip_bfloat16 lA[2][2][128*64];
  __shared__ __hip_bfloat16 lB[2][2][128*64];
  const int tid  = threadIdx.x;
  const int lane = tid & 63;
  const int mw = (tid >> 6) >> 2;        // 0..1
  const int nw = (tid >> 6) & 3;         // 0..3

  const int bid = blockIdx.x;            // 248 = 8 x 31
  const int swz = (bid & 7) * 31 + (bid >> 3);
  const int mt = swz >> 2, nt = swz & 3;
  const int tM = mt * 256, tN = nt * 256;
  const __hip_bfloat16* W = (mt < 23) ? Wh : Wl;

  const int srow = tid >> 3;             // 0..63
  const int schunk = tid & 7;            // 0..7

  auto stageA = [&](int par, int ht, int t){
    #pragma unroll
    for (int r = 0; r < 2; ++r){
      int ri = r*64 + srow;
      int grow = tM + ht*128 + ri;
      int gcol = t*64 + ((schunk ^ (ri & 7)) * 8);
      __builtin_amdgcn_global_load_lds(
        (const __attribute__((address_space(1))) void*)(A + (size_t)grow*1024 + gcol),
        (__attribute__((address_space(3))) void*)(&lA[par][ht][ri*64 + schunk*8]), 16, 0, 0);
    }
  };
  auto stageB = [&](int par, int ht, int t){
    #pragma unroll
    for (int r = 0; r < 2; ++r){
      int ri = r*64 + srow;
      int grow = tN + ht*128 + ri;
      int gcol = t*64 + ((schunk ^ (ri & 7)) * 8);
      __builtin_amdgcn_global_load_lds(
        (const __attribute__((address_space(1))) void*)(W + (size_t)grow*1024 + gcol),
        (__attribute__((address_space(3))) void*)(&lB[par][ht][ri*64 + schunk*8]), 16, 0, 0);
    }
  };

  f32x4 acc[2][2][4][2] = {};   // [mh][nh][fi][fj]

  // phase body: ds_read quadrant (mh,nh) of buf par, then (stage done by caller), barrier, MFMA, barrier
  auto phase_mfma = [&](int par, int mh, int nh){
    bf16x8 af[4][2], bf_[2][2];
    #pragma unroll
    for (int fi = 0; fi < 4; ++fi){
      #pragma unroll
      for (int kk = 0; kk < 2; ++kk){
        int ri = mw*64 + fi*16 + (lane & 15);
        int c  = (kk*32 + (lane >> 4)*8) ^ ((ri & 7)*8);
        af[fi][kk] = *(const bf16x8*)(&lA[par][mh][ri*64 + c]);
      }
    }
    #pragma unroll
    for (int fj = 0; fj < 2; ++fj){
      #pragma unroll
      for (int kk = 0; kk < 2; ++kk){
        int ri = nw*32 + fj*16 + (lane & 15);
        int c  = (kk*32 + (lane >> 4)*8) ^ ((ri & 7)*8);
        bf_[fj][kk] = *(const bf16x8*)(&lB[par][nh][ri*64 + c]);
      }
    }
    __builtin_amdgcn_s_barrier();
    __builtin_amdgcn_s_setprio(1);
    #pragma unroll
    for (int fi = 0; fi < 4; ++fi){
      #pragma unroll
      for (int fj = 0; fj < 2; ++fj){
        #pragma unroll
        for (int kk = 0; kk < 2; ++kk){
          f32x4* pacc = &acc[0][0][0][0] + ((mh*2 + nh)*4 + fi)*2 + fj;
          *pacc = __builtin_amdgcn_mfma_f32_16x16x32_bf16(af[fi][kk], bf_[fj][kk], *pacc, 0, 0, 0);
        }
      }
    }
    __builtin_amdgcn_s_setprio(0);
    __builtin_amdgcn_s_barrier();
  };

  // prologue: A0(0),B0(0),B1(0),A1(0),A0(1),B0(1)  = 12 loads/thread
  stageA(0, 0, 0); stageB(0, 0, 0); stageB(0, 1, 0); stageA(0, 1, 0);
  stageA(1, 0, 1); stageB(1, 0, 1);

  #pragma unroll 1
  for (int t = 0; t < 15; ++t){
    const int par = t & 1;
    // ph(0,0): needs A0(t),B0(t); stage B1(t+1) -> par^1
    vwait<8>();
    { bf16x8 dummy; (void)dummy; }
    stageB(par ^ 1, 1, t + 1);
    phase_mfma(par, 0, 0);
    // ph(0,1): needs B1(t); stage A1(t+1) -> par^1
    vwait<8>();
    stageA(par ^ 1, 1, t + 1);
    phase_mfma(par, 0, 1);
    // ph(1,0): needs A1(t); stage A0(t+2) -> par   (skip when t+2 > 15)
    vwait<8>();
    if (t + 2 <= 15) stageA(par, 0, t + 2);
    phase_mfma(par, 1, 0);
    // ph(1,1): no wait; stage B0(t+2) -> par
    if (t + 2 <= 15) stageB(par, 0, t + 2);
    phase_mfma(par, 1, 1);
  }
  // t = 15 (par = 1), no stages; waits {4,2,0,-}
  {
    vwait<4>();
    phase_mfma(1, 0, 0);
    vwait<2>();
    phase_mfma(1, 0, 1);
    vwait<0>();
    phase_mfma(1, 1, 0);
    phase_mfma(1, 1, 1);
  }

  // epilogue: bf16 VW store
  #pragma unroll
  for (int mh = 0; mh < 2; ++mh){
    #pragma unroll
    for (int nh = 0; nh < 2; ++nh){
      #pragma unroll
      for (int fi = 0; fi < 4; ++fi){
        #pragma unroll
        for (int fj = 0; fj < 2; ++fj){
          #pragma unroll
          for (int j = 0; j < 4; ++j){
            int row = tM + mh*128 + mw*64 + fi*16 + (lane >> 4)*4 + j;
            int col = tN + nh*128 + nw*32 + fj*16 + (lane & 15);
            VW[(size_t)row * 1024 + col] = __float2bfloat16(acc[mh][nh][fi][fj][j]);
          }
        }
      }
    }
  }
}

// ---------------- mix: softmax (from 4 Sp quarter-partials) + out = P @ VW + bias ----------------
template<int MODE>
DEV void mix_group(int g, int sh, int tid,
    const float* __restrict__ Sp, const float* __restrict__ pe,
    const __hip_bfloat16* __restrict__ VW, const float* __restrict__ bias,
    float* __restrict__ out, float* lds_p)
{
  constexpr int U  = (MODE == 0) ? 23 : 13;
  constexpr int UP = (MODE == 0) ? 24 : 16;
  int gm = (MODE == 0) ? g : g - 256;
  int b, h, d;
  if (MODE == 0){ b = gm >> 6; h = 0; d = gm & 63; }
  else { b = gm / 192; int rem = gm % 192; h = rem >> 6; d = rem & 63; }

  {
    int r = tid >> 3, c0 = (tid & 7) * 4;
    const float* A0 = Sp + (size_t)(4*g) * 1088;
    const float* A1 = A0 + 1088;
    const float* A2 = A0 + 2176;
    const float* A3 = A0 + 3264;
    float qn = A0[1024 + r] + A1[1024 + r] + A2[1024 + r] + A3[1024 + r];
    float iqn = 1.0f / fmaxf(sqrtf(qn), 1e-12f);
    float vals[4];
    #pragma unroll
    for (int j = 0; j < 4; ++j){
      int c = c0 + j;
      bool valid = (r < 23) && (c < U);
      if (valid){
        float sv = A0[r*32 + c] + A1[r*32 + c] + A2[r*32 + c] + A3[r*32 + c];
        float kn = A0[1056 + c] + A1[1056 + c] + A2[1056 + c] + A3[1056 + c];
        float ikn = 1.0f / fmaxf(sqrtf(kn), 1e-12f);
        float pv = (MODE == 0) ? pe[r*23 + c] : pe[(h*23 + r)*13 + c];
        vals[j] = sv * iqn * ikn + pv;
      } else vals[j] = -3.0e38f;
    }
    float m = fmaxf(fmaxf(vals[0], vals[1]), fmaxf(vals[2], vals[3]));
    m = fmaxf(m, __shfl_xor(m, 1)); m = fmaxf(m, __shfl_xor(m, 2)); m = fmaxf(m, __shfl_xor(m, 4));
    float e[4], ssum = 0.f;
    #pragma unroll
    for (int j = 0; j < 4; ++j){ e[j] = __expf(vals[j] - m); ssum += e[j]; }
    ssum += __shfl_xor(ssum, 1); ssum += __shfl_xor(ssum, 2); ssum += __shfl_xor(ssum, 4);
    float inv = 1.0f / ssum;
    if (r < 23){
      #pragma unroll
      for (int j = 0; j < 4; ++j)
        lds_p[r*32 + c0 + j] = (c0 + j < U) ? e[j] * inv : 0.f;
    }
  }
  __syncthreads();

  const int s0 = sh*512 + tid*2;
  const uint16_t* vwb = (const uint16_t*)VW +
      ((MODE == 0) ? (size_t)g*23*1024 : (size_t)(5888 + gm*13)*1024) + s0;
  float2 vv[UP];
  #pragma unroll
  for (int u = 0; u < UP; ++u){
    if (u < U){
      uint32_t w2 = *(const uint32_t*)(vwb + (size_t)u*1024);
      vv[u].x = bflo(w2); vv[u].y = bfhi(w2);
    } else { vv[u].x = 0.f; vv[u].y = 0.f; }
  }
  const float bx = bias[s0], by = bias[s0 + 1];
  const int orow0 = (MODE == 0) ? (b*5888 + d*23) : (b*5888 + (1 + h)*1472 + d*23);

  #pragma unroll 2
  for (int t = 0; t < 23; ++t){
    float ax = bx, ay = by;
    #pragma unroll
    for (int u4 = 0; u4 < UP/4; ++u4){
      float4 p = *(const float4*)(lds_p + t*32 + u4*4);
      ax += p.x*vv[u4*4+0].x + p.y*vv[u4*4+1].x + p.z*vv[u4*4+2].x + p.w*vv[u4*4+3].x;
      ay += p.x*vv[u4*4+0].y + p.y*vv[u4*4+1].y + p.z*vv[u4*4+2].y + p.w*vv[u4*4+3].y;
    }
    float2 o2; o2.x = ax; o2.y = ay;
    *(float2*)(out + (size_t)(orow0 + t)*1024 + s0) = o2;
  }
}

__global__ __launch_bounds__(256) void mix_all(
    const float* __restrict__ Sp, const float* __restrict__ pe_h, const float* __restrict__ pe_l,
    const __hip_bfloat16* __restrict__ VW,
    const float* __restrict__ hb, const float* __restrict__ lb,
    float* __restrict__ out)
{
  __shared__ __align__(16) float lds_p[23*32];
  int bid = blockIdx.x;
  int g = bid >> 1, sh = bid & 1;
  if (g < 256) mix_group<0>(g, sh, threadIdx.x, Sp, pe_h, VW, hb, out, lds_p);
  else         mix_group<1>(g, sh, threadIdx.x, Sp, pe_l, VW, lb, out, lds_p);
}

extern "C" void kernel_launch(void* const* d_in, const int* in_sizes, int n_in,
                              void* d_out, int out_size, void* d_ws, size_t ws_size,
                              hipStream_t stream) {
  const float* xh0  = (const float*)d_in[0];
  const float* xh1  = (const float*)d_in[1];
  const float* xh2  = (const float*)d_in[2];
  const float* xl0  = (const float*)d_in[3];
  const float* xl1  = (const float*)d_in[4];
  const float* xl2  = (const float*)d_in[5];
  const float* htab = (const float*)d_in[6];
  const float* habs = (const float*)d_in[7];
  const float* ltab = (const float*)d_in[8];
  const float* labs = (const float*)d_in[9];
  const float* hw   = (const float*)d_in[10];
  const float* hb   = (const float*)d_in[11];
  const float* lw   = (const float*)d_in[12];
  const float* lb   = (const float*)d_in[13];
  float* out = (float*)d_out;

  char* ws = (char*)d_ws;
  float* pe_h = (float*)ws;                                   // 529 f32
  float* pe_l = (float*)(ws + 2176);                          // 897 f32
  __hip_bfloat16* VW  = (__hip_bfloat16*)(ws + 8192);         // 15872x1024 bf16 = 32.5 MB
  float* Sp           = (float*)(ws + 8192 + 32505856);       // 4096x1088 f32 = 17.8 MB

  // d_out scratch aliases (all consumed before mix overwrites out):
  __hip_bfloat16* Vb  = (__hip_bfloat16*)out;
  __hip_bfloat16* whb = (__hip_bfloat16*)(out + 23068672);    // 1M bf16
  __hip_bfloat16* wlb = whb + 1048576;                        // 1M bf16

  fused_a<<<7106, 256, 0, stream>>>(xh0, xh1, xh2, xl0, xl1, xl2,
                                    htab, habs, ltab, labs, hw, lw,
                                    Sp, Vb, pe_h, pe_l, whb, wlb);
  gemm8<<<248, 512, 0, stream>>>(Vb, whb, wlb, VW);
  mix_all<<<2048, 256, 0, stream>>>(Sp, pe_h, pe_l, VW, hb, lb, out);
}

// Round 15
// 152.824 us; speedup vs baseline: 1.0451x; 1.0451x over previous
//
#include <hip/hip_runtime.h>
#include <hip/hip_bf16.h>
#include <stdint.h>

#define DEV __device__ __forceinline__

typedef float f32x4 __attribute__((ext_vector_type(4)));
typedef __bf16 bf16x8 __attribute__((ext_vector_type(8)));

DEV __bf16 tobf(float x){
  union { __hip_bfloat16 s; __bf16 b; } u; u.s = __float2bfloat16(x); return u.b;
}
DEV float bflo(uint32_t u){ return __uint_as_float(u << 16); }
DEV float bfhi(uint32_t u){ return __uint_as_float(u & 0xffff0000u); }
DEV float dot4(const float4& a, const float4& b){
  return a.x*b.x + a.y*b.y + a.z*b.z + a.w*b.w;
}
DEV bf16x8 pack8(const float4& a, const float4& b){
  bf16x8 r;
  r[0]=tobf(a.x); r[1]=tobf(a.y); r[2]=tobf(a.z); r[3]=tobf(a.w);
  r[4]=tobf(b.x); r[5]=tobf(b.y); r[6]=tobf(b.z); r[7]=tobf(b.w);
  return r;
}
DEV uint32_t f2bf2(float x, float y){
  union { __hip_bfloat16 b[2]; uint32_t u; } cv;
  cv.b[0] = __float2bfloat16(x); cv.b[1] = __float2bfloat16(y);
  return cv.u;
}
DEV float4 avg4(const float4& a, const float4& b){
  float4 r; r.x=0.5f*(a.x+b.x); r.y=0.5f*(a.y+b.y); r.z=0.5f*(a.z+b.z); r.w=0.5f*(a.w+b.w);
  return r;
}

// relative-coordinate values (matches reference _rel_index, f32 semantics)
DEV float relc(int j){
  if (j < 17) return (float)(j - 8);
  if (j < 22) return (float)(j - 19) * 3.4f;   // (i-2) * 17/5
  return 0.0f;
}
DEV int band_of(int t){ return t < 17 ? 0 : (t < 22 ? 1 : 2); }

// avgpool1d index map over the concatenated 23-axis -> 13 pooled slots.
template<int MODE> DEV void pool_map(int u, int& a, int& b){
  if (MODE == 0){ a = u; b = u; return; }
  if (u == 0){ a = 0; b = 0; }
  else if (u < 9){ a = 2*u - 1; b = 2*u; }
  else if (u == 9){ a = 17; b = 17; }
  else if (u < 12){ a = 2*u - 2; b = 2*u - 1; }
  else { a = 22; b = 22; }
}

DEV float interp_tab(const float* tab, int H, int h, int t, int u){
  float idx = relc(t) - relc(u) + 16.0f;
  float fl = floorf(idx);
  float ce = ceilf(idx);
  int fi = (int)fminf(fmaxf(fl, 0.f), 1088.f);
  int ci = (int)fminf(fmaxf(ce, 0.f), 1088.f);
  float w = idx - fl;
  return (1.0f - w) * tab[fi*H + h] + w * tab[ci*H + h];
}

// ---------------- QK^T quarter-partial: flat-load version (r11-proven) ----------------
template<int MODE>
DEV void qk_group(int gm, int qt,
    const float* __restrict__ x0, const float* __restrict__ x1, const float* __restrict__ x2,
    float* __restrict__ SpB,
    float* Spart /*[4][32][33]*/, float* qnp /*[4][32]*/, float* knp /*[4][32]*/)
{
  constexpr int U = (MODE == 0) ? 23 : 13;
  constexpr int H = (MODE == 0) ? 1 : 3;
  int b, h, d;
  if (MODE == 0){ b = gm >> 6; h = 0; d = gm & 63; }
  else { b = gm / 192; int r = gm % 192; h = r >> 6; d = r & 63; }

  const int tid  = threadIdx.x;
  const int lane = tid & 63;
  const int w    = tid >> 6;
  const int lrow = lane & 15;
  const int kq   = lane >> 4;

  auto base_of = [&](int sel, int band) -> const float* {
    if (band == 0) return x0 + (size_t)((((sel*4 + b)*H + h)*64 + d)*17) * 1024;
    if (band == 1) return x1 + (size_t)((((sel*4 + b)*H + h)*64 + d)*5) * 1024;
    return x2 + (size_t)(((sel*4 + b)*H + h)*64 + d) * 1024;
  };
  const float* qb0 = base_of(0,0); const float* qb1 = base_of(0,1); const float* qb2 = base_of(0,2);
  const float* kb0 = base_of(1,0); const float* kb1 = base_of(1,1); const float* kb2 = base_of(1,2);

  auto rowp = [&](const float* r0, const float* r1, const float* r2, int t) -> const float* {
    if (t < 17) return r0 + (size_t)t * 1024;
    if (t < 22) return r1 + (size_t)(t - 17) * 1024;
    return r2;
  };

  const float* qr[2]; bool qv[2];
  #pragma unroll
  for (int mi = 0; mi < 2; ++mi){
    int t = mi*16 + lrow;
    qv[mi] = (t < 23);
    qr[mi] = qv[mi] ? rowp(qb0,qb1,qb2,t) : qb0;
  }
  const float* krA[2]; const float* krB[2]; bool kv[2];
  #pragma unroll
  for (int ni = 0; ni < 2; ++ni){
    int u = ni*16 + lrow;
    kv[ni] = (u < U);
    int au, bu; pool_map<MODE>(kv[ni] ? u : 0, au, bu);
    krA[ni] = rowp(kb0,kb1,kb2,au);
    krB[ni] = rowp(kb0,kb1,kb2,bu);
  }

  const int sbase = qt*256 + w*64 + kq*8;

  float4 qld[2][4];
  float4 kld[2][4];
  #pragma unroll
  for (int mi = 0; mi < 2; ++mi){
    #pragma unroll
    for (int kk = 0; kk < 2; ++kk){
      #pragma unroll
      for (int hf = 0; hf < 2; ++hf){
        qld[mi][kk*2+hf] = qv[mi] ? *(const float4*)(qr[mi] + sbase + kk*32 + hf*4)
                                  : float4{0,0,0,0};
      }
    }
  }
  if (MODE == 0){
    #pragma unroll
    for (int ni = 0; ni < 2; ++ni){
      #pragma unroll
      for (int kk = 0; kk < 2; ++kk){
        #pragma unroll
        for (int hf = 0; hf < 2; ++hf){
          kld[ni][kk*2+hf] = kv[ni] ? *(const float4*)(krA[ni] + sbase + kk*32 + hf*4)
                                    : float4{0,0,0,0};
        }
      }
    }
  } else {
    #pragma unroll
    for (int kk = 0; kk < 2; ++kk){
      #pragma unroll
      for (int hf = 0; hf < 2; ++hf){
        kld[0][kk*2+hf] = kv[0] ? *(const float4*)(krA[0] + sbase + kk*32 + hf*4)
                                : float4{0,0,0,0};
        kld[1][kk*2+hf] = kv[0] ? *(const float4*)(krB[0] + sbase + kk*32 + hf*4)
                                : float4{0,0,0,0};
      }
    }
  }

  f32x4 acc[2][2] = {};
  float qss[2] = {0.f, 0.f}, kss[2] = {0.f, 0.f};
  #pragma unroll
  for (int kk = 0; kk < 2; ++kk){
    bf16x8 qf[2], kf[2];
    #pragma unroll
    for (int mi = 0; mi < 2; ++mi){
      float4 v0 = qld[mi][kk*2], v1 = qld[mi][kk*2+1];
      qss[mi] += dot4(v0,v0) + dot4(v1,v1);
      qf[mi] = pack8(v0, v1);
    }
    if (MODE == 0){
      #pragma unroll
      for (int ni = 0; ni < 2; ++ni){
        float4 v0 = kld[ni][kk*2], v1 = kld[ni][kk*2+1];
        kss[ni] += dot4(v0,v0) + dot4(v1,v1);
        kf[ni] = pack8(v0, v1);
      }
    } else {
      float4 v0 = avg4(kld[0][kk*2], kld[1][kk*2]);
      float4 v1 = avg4(kld[0][kk*2+1], kld[1][kk*2+1]);
      kss[0] += dot4(v0,v0) + dot4(v1,v1);
      kf[0] = pack8(v0, v1);
    }
    #pragma unroll
    for (int mi = 0; mi < 2; ++mi){
      #pragma unroll
      for (int ni = 0; ni < 2; ++ni){
        if (MODE == 0 || ni == 0)
          acc[mi][ni] = __builtin_amdgcn_mfma_f32_16x16x32_bf16(qf[mi], kf[ni], acc[mi][ni], 0, 0, 0);
      }
    }
  }

  #pragma unroll
  for (int i = 0; i < 2; ++i){
    qss[i] += __shfl_xor(qss[i], 16); qss[i] += __shfl_xor(qss[i], 32);
    kss[i] += __shfl_xor(kss[i], 16); kss[i] += __shfl_xor(kss[i], 32);
  }
  if (lane < 16){
    qnp[w*32 + lane]      = qss[0];
    qnp[w*32 + 16 + lane] = qss[1];
    knp[w*32 + lane]      = kss[0];
    knp[w*32 + 16 + lane] = kss[1];
  }
  #pragma unroll
  for (int mi = 0; mi < 2; ++mi)
    #pragma unroll
    for (int ni = 0; ni < 2; ++ni)
      #pragma unroll
      for (int j = 0; j < 4; ++j)
        Spart[w*1056 + (mi*16 + kq*4 + j)*33 + ni*16 + lrow] = acc[mi][ni][j];
  __syncthreads();

  if (tid < 32){
    SpB[1024 + tid] = qnp[tid] + qnp[32+tid] + qnp[64+tid] + qnp[96+tid];
  } else if (tid < 64){
    int c = tid - 32;
    SpB[1056 + c] = knp[c] + knp[32+c] + knp[64+c] + knp[96+c];
  }
  {
    int r  = tid >> 3;
    int c0 = (tid & 7) * 4;
    float4 o;
    o.x = Spart[r*33+c0+0] + Spart[1056+r*33+c0+0] + Spart[2112+r*33+c0+0] + Spart[3168+r*33+c0+0];
    o.y = Spart[r*33+c0+1] + Spart[1056+r*33+c0+1] + Spart[2112+r*33+c0+1] + Spart[3168+r*33+c0+1];
    o.z = Spart[r*33+c0+2] + Spart[1056+r*33+c0+2] + Spart[2112+r*33+c0+2] + Spart[3168+r*33+c0+2];
    o.w = Spart[r*33+c0+3] + Spart[1056+r*33+c0+3] + Spart[2112+r*33+c0+3] + Spart[3168+r*33+c0+3];
    *(float4*)(SpB + r*32 + c0) = o;
  }
}

// ---------------- fused_a: qk4 [0,4096) + vconv [4096,6080) + prep [6080,7106) ----------------
__global__ __launch_bounds__(256, 4) void fused_a(
    const float* __restrict__ xh0, const float* __restrict__ xh1, const float* __restrict__ xh2,
    const float* __restrict__ xl0, const float* __restrict__ xl1, const float* __restrict__ xl2,
    const float* __restrict__ htab, const float* __restrict__ habs,
    const float* __restrict__ ltab, const float* __restrict__ labs,
    const float* __restrict__ hw, const float* __restrict__ lw,
    float* __restrict__ Sp, __hip_bfloat16* __restrict__ Vb,
    float* __restrict__ pe_h, float* __restrict__ pe_l,
    __hip_bfloat16* __restrict__ whb, __hip_bfloat16* __restrict__ wlb)
{
  __shared__ __align__(16) float Spart[4*32*33];
  __shared__ float qnp[4*32], knp[4*32];
  const int bid = blockIdx.x;
  const int tid = threadIdx.x;

  if (bid < 4096){
    int g = bid >> 2, qt = bid & 3;
    float* SpB = Sp + (size_t)bid * 1088;
    if (g < 256) qk_group<0>(g,       qt, xh0, xh1, xh2, SpB, Spart, qnp, knp);
    else         qk_group<1>(g - 256, qt, xl0, xl1, xl2, SpB, Spart, qnp, knp);
    return;
  }

  if (bid < 6080){
    // ---- vconv: pooled V -> bf16, 8 rows per block, flat-loaded ----
    const int vb_ = bid - 4096;
    auto vsrc = [&](int r, const float*& pa, const float*& pb){
      if (r < 5888){
        int gg = r / 23, u = r - gg*23;
        int b = gg >> 6, d = gg & 63;
        const float* v0 = xh0 + (size_t)(((8 + b)*64 + d)*17) * 1024;
        const float* v1 = xh1 + (size_t)(((8 + b)*64 + d)*5) * 1024;
        const float* v2 = xh2 + (size_t)((8 + b)*64 + d) * 1024;
        pa = (u < 17) ? v0 + (size_t)u*1024 : (u < 22 ? v1 + (size_t)(u-17)*1024 : v2);
        pb = pa;
      } else {
        int rr = r - 5888;
        int gm = rr / 13, u = rr - gm*13;
        int b = gm / 192, rem = gm % 192, h = rem >> 6, d = rem & 63;
        const float* v0 = xl0 + (size_t)((((8 + b)*3 + h)*64 + d)*17) * 1024;
        const float* v1 = xl1 + (size_t)((((8 + b)*3 + h)*64 + d)*5) * 1024;
        const float* v2 = xl2 + (size_t)(((8 + b)*3 + h)*64 + d) * 1024;
        int au, bu; pool_map<1>(u, au, bu);
        pa = (au < 17) ? v0 + (size_t)au*1024 : (au < 22 ? v1 + (size_t)(au-17)*1024 : v2);
        pb = (bu < 17) ? v0 + (size_t)bu*1024 : (bu < 22 ? v1 + (size_t)(bu-17)*1024 : v2);
      }
    };
    const int c0 = tid * 4;
    float4 va[8], vbv[8]; bool two[8];
    #pragma unroll
    for (int i = 0; i < 8; ++i){
      int r = vb_*8 + i;
      const float *pa, *pb; vsrc(r, pa, pb);
      va[i] = *(const float4*)(pa + c0);
      two[i] = (pb != pa);
      vbv[i] = two[i] ? *(const float4*)(pb + c0) : va[i];
    }
    #pragma unroll
    for (int i = 0; i < 8; ++i){
      float4 a = two[i] ? avg4(va[i], vbv[i]) : va[i];
      uint2 o; o.x = f2bf2(a.x, a.y); o.y = f2bf2(a.z, a.w);
      *(uint2*)(Vb + (size_t)(vb_*8 + i)*1024 + c0) = o;
    }
    return;
  }

  // ---- prep ----
  const int pb_ = bid - 6080;
  if (pb_ < 1024){
    int i = (pb_*256 + tid)*8;
    const float* src; __hip_bfloat16* dst;
    if (i < 1048576){ src = hw + i; dst = whb + i; }
    else { src = lw + (i - 1048576); dst = wlb + (i - 1048576); }
    float4 x0 = *(const float4*)(src);
    float4 x1 = *(const float4*)(src + 4);
    uint4 o;
    o.x = f2bf2(x0.x, x0.y); o.y = f2bf2(x0.z, x0.w);
    o.z = f2bf2(x1.x, x1.y); o.w = f2bf2(x1.z, x1.w);
    *(uint4*)dst = o;
  } else if (pb_ == 1024){
    for (int j = tid; j < 529; j += 256){
      int t = j / 23, u = j % 23;
      pe_h[j] = interp_tab(htab, 1, 0, t, u) + habs[band_of(t)];
    }
  } else {
    for (int j = tid; j < 897; j += 256){
      int h = j / 299, r = j % 299, t = r / 13, u = r % 13;
      int a, b; pool_map<1>(u, a, b);
      pe_l[j] = 0.5f * (interp_tab(ltab, 3, h, t, a) + interp_tab(ltab, 3, h, t, b))
              + labs[band_of(t)*3 + h];
    }
  }
}

// ---------------- VW GEMM (r4-proven structure): VW[r][n] = sum_k Vb[r][k] * W[n][k] ----------------
__global__ __launch_bounds__(256) void gemm_vw(
    const __hip_bfloat16* __restrict__ A,
    const __hip_bfloat16* __restrict__ Wh, const __hip_bfloat16* __restrict__ Wl,
    __hip_bfloat16* __restrict__ VW)
{
  __shared__ __hip_bfloat16 lA[2][128*64];
  __shared__ __hip_bfloat16 lB[2][128*64];
  const int tid  = threadIdx.x;
  const int lane = tid & 63;

  const int bid = blockIdx.x;
  const int swz = (bid & 7) * 124 + (bid >> 3);
  const int mt = swz >> 3, nt = swz & 7;
  const int tM = mt * 128, tN = nt * 128;
  const bool hifi = (mt < 46);
  const __hip_bfloat16* W = hifi ? Wh : Wl;

  const int wm = ((tid >> 6) >> 1) * 64, wn = ((tid >> 6) & 1) * 64;
  f32x4 acc[4][4] = {};

  const int srow = tid >> 3;
  const int scol = ((tid & 7) * 8) ^ ((srow & 7) * 8);
  const __hip_bfloat16* ga = A + (size_t)(tM + srow) * 1024 + scol;
  const __hip_bfloat16* gb = W + (size_t)(tN + srow) * 1024 + scol;

  auto stage = [&](int buf, int k0){
    #pragma unroll
    for (int q = 0; q < 4; ++q){
      __builtin_amdgcn_global_load_lds(
        (const __attribute__((address_space(1))) void*)(ga + k0 + (size_t)q*32*1024),
        (__attribute__((address_space(3))) void*)(&lA[buf][q*2048 + tid*8]), 16, 0, 0);
      __builtin_amdgcn_global_load_lds(
        (const __attribute__((address_space(1))) void*)(gb + k0 + (size_t)q*32*1024),
        (__attribute__((address_space(3))) void*)(&lB[buf][q*2048 + tid*8]), 16, 0, 0);
    }
  };

  const int rsw = (lane & 7) * 8;
  auto compute = [&](int buf){
    #pragma unroll
    for (int kk = 0; kk < 2; ++kk){
      const int cb = (kk*32 + (lane >> 4)*8) ^ rsw;
      bf16x8 af[4], bfr[4];
      #pragma unroll
      for (int mi = 0; mi < 4; ++mi)
        af[mi] = *(const bf16x8*)(&lA[buf][(wm + mi*16 + (lane & 15))*64 + cb]);
      #pragma unroll
      for (int ni = 0; ni < 4; ++ni)
        bfr[ni] = *(const bf16x8*)(&lB[buf][(wn + ni*16 + (lane & 15))*64 + cb]);
      #pragma unroll
      for (int mi = 0; mi < 4; ++mi){
        #pragma unroll
        for (int ni = 0; ni < 4; ++ni)
          acc[mi][ni] = __builtin_amdgcn_mfma_f32_16x16x32_bf16(af[mi], bfr[ni], acc[mi][ni], 0, 0, 0);
      }
    }
  };

  stage(0, 0);
  __syncthreads();
  int cur = 0;
  #pragma unroll 1
  for (int t = 0; t < 15; ++t){
    stage(cur ^ 1, (t + 1) * 64);
    compute(cur);
    __syncthreads();
    cur ^= 1;
  }
  compute(cur);

  #pragma unroll
  for (int mi = 0; mi < 4; ++mi){
    #pragma unroll
    for (int j = 0; j < 4; ++j){
      int r = tM + wm + mi*16 + (lane >> 4)*4 + j;
      __hip_bfloat16* po = VW + (size_t)r * 1024 + tN + wn + (lane & 15);
      #pragma unroll
      for (int ni = 0; ni < 4; ++ni)
        po[ni*16] = __float2bfloat16(acc[mi][ni][j]);
    }
  }
}

// ---------------- mix: softmax (from 4 Sp quarter-partials) + out = P @ VW + bias ----------------
template<int MODE>
DEV void mix_group(int g, int sh, int tid,
    const float* __restrict__ Sp, const float* __restrict__ pe,
    const __hip_bfloat16* __restrict__ VW, const float* __restrict__ bias,
    float* __restrict__ out, float* lds_p)
{
  constexpr int U  = (MODE == 0) ? 23 : 13;
  constexpr int UP = (MODE == 0) ? 24 : 16;
  int gm = (MODE == 0) ? g : g - 256;
  int b, h, d;
  if (MODE == 0){ b = gm >> 6; h = 0; d = gm & 63; }
  else { b = gm / 192; int rem = gm % 192; h = rem >> 6; d = rem & 63; }

  {
    int r = tid >> 3, c0 = (tid & 7) * 4;
    const float* A0 = Sp + (size_t)(4*g) * 1088;
    const float* A1 = A0 + 1088;
    const float* A2 = A0 + 2176;
    const float* A3 = A0 + 3264;
    float qn = A0[1024 + r] + A1[1024 + r] + A2[1024 + r] + A3[1024 + r];
    float iqn = 1.0f / fmaxf(sqrtf(qn), 1e-12f);
    float vals[4];
    #pragma unroll
    for (int j = 0; j < 4; ++j){
      int c = c0 + j;
      bool valid = (r < 23) && (c < U);
      if (valid){
        float sv = A0[r*32 + c] + A1[r*32 + c] + A2[r*32 + c] + A3[r*32 + c];
        float kn = A0[1056 + c] + A1[1056 + c] + A2[1056 + c] + A3[1056 + c];
        float ikn = 1.0f / fmaxf(sqrtf(kn), 1e-12f);
        float pv = (MODE == 0) ? pe[r*23 + c] : pe[(h*23 + r)*13 + c];
        vals[j] = sv * iqn * ikn + pv;
      } else vals[j] = -3.0e38f;
    }
    float m = fmaxf(fmaxf(vals[0], vals[1]), fmaxf(vals[2], vals[3]));
    m = fmaxf(m, __shfl_xor(m, 1)); m = fmaxf(m, __shfl_xor(m, 2)); m = fmaxf(m, __shfl_xor(m, 4));
    float e[4], ssum = 0.f;
    #pragma unroll
    for (int j = 0; j < 4; ++j){ e[j] = __expf(vals[j] - m); ssum += e[j]; }
    ssum += __shfl_xor(ssum, 1); ssum += __shfl_xor(ssum, 2); ssum += __shfl_xor(ssum, 4);
    float inv = 1.0f / ssum;
    if (r < 23){
      #pragma unroll
      for (int j = 0; j < 4; ++j)
        lds_p[r*32 + c0 + j] = (c0 + j < U) ? e[j] * inv : 0.f;
    }
  }
  __syncthreads();

  const int s0 = sh*512 + tid*2;
  const uint16_t* vwb = (const uint16_t*)VW +
      ((MODE == 0) ? (size_t)g*23*1024 : (size_t)(5888 + gm*13)*1024) + s0;
  float2 vv[UP];
  #pragma unroll
  for (int u = 0; u < UP; ++u){
    if (u < U){
      uint32_t w2 = *(const uint32_t*)(vwb + (size_t)u*1024);
      vv[u].x = bflo(w2); vv[u].y = bfhi(w2);
    } else { vv[u].x = 0.f; vv[u].y = 0.f; }
  }
  const float bx = bias[s0], by = bias[s0 + 1];
  const int orow0 = (MODE == 0) ? (b*5888 + d*23) : (b*5888 + (1 + h)*1472 + d*23);

  #pragma unroll 2
  for (int t = 0; t < 23; ++t){
    float ax = bx, ay = by;
    #pragma unroll
    for (int u4 = 0; u4 < UP/4; ++u4){
      float4 p = *(const float4*)(lds_p + t*32 + u4*4);
      ax += p.x*vv[u4*4+0].x + p.y*vv[u4*4+1].x + p.z*vv[u4*4+2].x + p.w*vv[u4*4+3].x;
      ay += p.x*vv[u4*4+0].y + p.y*vv[u4*4+1].y + p.z*vv[u4*4+2].y + p.w*vv[u4*4+3].y;
    }
    float2 o2; o2.x = ax; o2.y = ay;
    *(float2*)(out + (size_t)(orow0 + t)*1024 + s0) = o2;
  }
}

__global__ __launch_bounds__(256) void mix_all(
    const float* __restrict__ Sp, const float* __restrict__ pe_h, const float* __restrict__ pe_l,
    const __hip_bfloat16* __restrict__ VW,
    const float* __restrict__ hb, const float* __restrict__ lb,
    float* __restrict__ out)
{
  __shared__ __align__(16) float lds_p[23*32];
  int bid = blockIdx.x;
  int g = bid >> 1, sh = bid & 1;
  if (g < 256) mix_group<0>(g, sh, threadIdx.x, Sp, pe_h, VW, hb, out, lds_p);
  else         mix_group<1>(g, sh, threadIdx.x, Sp, pe_l, VW, lb, out, lds_p);
}

extern "C" void kernel_launch(void* const* d_in, const int* in_sizes, int n_in,
                              void* d_out, int out_size, void* d_ws, size_t ws_size,
                              hipStream_t stream) {
  const float* xh0  = (const float*)d_in[0];
  const float* xh1  = (const float*)d_in[1];
  const float* xh2  = (const float*)d_in[2];
  const float* xl0  = (const float*)d_in[3];
  const float* xl1  = (const float*)d_in[4];
  const float* xl2  = (const float*)d_in[5];
  const float* htab = (const float*)d_in[6];
  const float* habs = (const float*)d_in[7];
  const float* ltab = (const float*)d_in[8];
  const float* labs = (const float*)d_in[9];
  const float* hw   = (const float*)d_in[10];
  const float* hb   = (const float*)d_in[11];
  const float* lw   = (const float*)d_in[12];
  const float* lb   = (const float*)d_in[13];
  float* out = (float*)d_out;

  char* ws = (char*)d_ws;
  float* pe_h = (float*)ws;                                   // 529 f32
  float* pe_l = (float*)(ws + 2176);                          // 897 f32
  __hip_bfloat16* VW  = (__hip_bfloat16*)(ws + 8192);         // 15872x1024 bf16 = 32.5 MB
  float* Sp           = (float*)(ws + 8192 + 32505856);       // 4096x1088 f32 = 17.8 MB

  // d_out scratch aliases (all consumed before mix overwrites out):
  //   Vb  = front 32.5 MB (fused_a writes, gemm reads)
  //   whb/wlb = tail 4 MB (fused_a writes, gemm reads)
  __hip_bfloat16* Vb  = (__hip_bfloat16*)out;
  __hip_bfloat16* whb = (__hip_bfloat16*)(out + 23068672);    // 1M bf16
  __hip_bfloat16* wlb = whb + 1048576;                        // 1M bf16

  fused_a<<<7106, 256, 0, stream>>>(xh0, xh1, xh2, xl0, xl1, xl2,
                                    htab, habs, ltab, labs, hw, lw,
                                    Sp, Vb, pe_h, pe_l, whb, wlb);
  gemm_vw<<<992, 256, 0, stream>>>(Vb, whb, wlb, VW);
  mix_all<<<2048, 256, 0, stream>>>(Sp, pe_h, pe_l, VW, hb, lb, out);
}